// Round 7
// baseline (126.036 us; speedup 1.0000x reference)
//
#include <hip/hip_runtime.h>

typedef unsigned int u32;
typedef unsigned short u16;
typedef _Float16 f16;
typedef __attribute__((ext_vector_type(8))) _Float16 f16x8;
typedef __attribute__((ext_vector_type(4))) float f32x4;

#define T_TOK 12544   // 4*56*56
#define EMB   256
#define IMG   56
// SCALE * log2(e): softmax via exp2 is mathematically identical
#define SCALE2 0.25503486f
#define HALO  196
#define KSTR  40      // sK row stride (u16)
#define VTSTR 208     // sVT row stride (u16) — must stay %8==0 for b128 PV reads
#define PSTR  136     // sP row stride (u16): 128-col window + 8 pad

__device__ __forceinline__ u16 f16b(float f) {
    const f16 h = (f16)f;                 // v_cvt_f16_f32, RTNE
    return __builtin_bit_cast(u16, h);
}
__device__ __forceinline__ u32 pk2(float lo, float hi) {
    return (u32)f16b(lo) | ((u32)f16b(hi) << 16);
}
__device__ __forceinline__ uint4 pk16(const float4 a, const float4 b) {
    uint4 r;
    r.x = pk2(a.x, a.y); r.y = pk2(a.z, a.w);
    r.z = pk2(b.x, b.y); r.w = pk2(b.z, b.w);
    return r;
}

// async global->LDS, 16B/lane; LDS dest must be wave-uniform base + lane*16
#define GLD16(g, l) __builtin_amdgcn_global_load_lds( \
    (const __attribute__((address_space(1))) u32*)(g), \
    (__attribute__((address_space(3))) u32*)(l), 16, 0, 0)

// ---------------------------------------------------------------------------
// QKV GEMM, 128x128 tile (588 blocks): 4 waves, each a 64x64 quadrant
// (acc 4x4). A,B staged directly from f32 (dwordx4 + cvt + ds_write_b128
// after the MFMA phase). SWAPPED mfma(B,A): lane owns one token with 4
// consecutive channels per reg-quad -> epilogue = 16x ushort4 stores.
// Double-buffered, 1 barrier/k-tile, XCD-chunked swizzle.
// Output HEAD-BLOCKED [head][token][32] f16.
// ---------------------------------------------------------------------------
__global__ __launch_bounds__(256) void qkv_mfma(
    const float* __restrict__ xf,
    const float* __restrict__ wq, const float* __restrict__ wk, const float* __restrict__ wv,
    const float* __restrict__ bq, const float* __restrict__ bk, const float* __restrict__ bv,
    u16* __restrict__ qb, u16* __restrict__ kb, u16* __restrict__ vb) {
    __shared__ __attribute__((aligned(16))) u16 sA[2][128 * 32];
    __shared__ __attribute__((aligned(16))) u16 sB[2][128 * 32];
    const int bid = blockIdx.y * 6 + blockIdx.x;
    const int xcd = bid & 7, loc = bid >> 3;
    const int work = (xcd < 4 ? xcd * 74 : 296 + (xcd - 4) * 73) + loc;
    const int nBase = (work % 6) * 128;            // 0..767 (stacked qkv)
    const int mBase = (work / 6) * 128;
    const int tid = threadIdx.x, wv_ = tid >> 6, ln = tid & 63;
    const int lrow = ln & 15, lqd = ln >> 4;
    const int wr = wv_ >> 1, wc = wv_ & 1;         // wave quadrant (2x2)

    const int which = nBase >> 8;   // 0=q, 1=k, 2=v (uniform per block)
    const float* wsrc = (which == 0) ? wq : (which == 1) ? wk : wv;
    const int nrow0 = nBase & 255;

    // staging map: thread -> (row = tid>>2 and +64, cols (tid&3)*8 .. +8)
    const int arow = tid >> 2, acol = (tid & 3) * 8;
    const float* gAf = xf   + (size_t)(mBase + arow) * EMB + acol;
    const float* gBf = wsrc + (size_t)(nrow0 + arow) * EMB + acol;
    const int so = tid * 8;                        // u16 offset (linear, conflict-free)

    f32x4 acc[4][4];
    #pragma unroll
    for (int mi = 0; mi < 4; ++mi)
        #pragma unroll
        for (int ni = 0; ni < 4; ++ni) acc[mi][ni] = (f32x4){0.f, 0.f, 0.f, 0.f};

    // prologue: stage k-tile 0 into buffer 0
    {
        const float4 ra0 = *(const float4*)(gAf);
        const float4 ra1 = *(const float4*)(gAf + 4);
        const float4 ra2 = *(const float4*)(gAf + 64 * EMB);
        const float4 ra3 = *(const float4*)(gAf + 64 * EMB + 4);
        const float4 rb0 = *(const float4*)(gBf);
        const float4 rb1 = *(const float4*)(gBf + 4);
        const float4 rb2 = *(const float4*)(gBf + 64 * EMB);
        const float4 rb3 = *(const float4*)(gBf + 64 * EMB + 4);
        *(uint4*)&sA[0][so]        = pk16(ra0, ra1);
        *(uint4*)&sA[0][2048 + so] = pk16(ra2, ra3);
        *(uint4*)&sB[0][so]        = pk16(rb0, rb1);
        *(uint4*)&sB[0][2048 + so] = pk16(rb2, rb3);
    }

    for (int kt = 0; kt < 8; ++kt) {
        const int b = kt & 1;
        __syncthreads();
        float4 ra0, ra1, ra2, ra3, rb0, rb1, rb2, rb3;
        if (kt < 7) {
            const int k0 = (kt + 1) * 32;
            ra0 = *(const float4*)(gAf + k0);
            ra1 = *(const float4*)(gAf + k0 + 4);
            ra2 = *(const float4*)(gAf + k0 + 64 * EMB);
            ra3 = *(const float4*)(gAf + k0 + 64 * EMB + 4);
            rb0 = *(const float4*)(gBf + k0);
            rb1 = *(const float4*)(gBf + k0 + 4);
            rb2 = *(const float4*)(gBf + k0 + 64 * EMB);
            rb3 = *(const float4*)(gBf + k0 + 64 * EMB + 4);
        }
        f16x8 af[4], bfr[4];
        #pragma unroll
        for (int mi = 0; mi < 4; ++mi)
            af[mi] = *(const f16x8*)&sA[b][(wr * 64 + mi * 16 + lrow) * 32 + lqd * 8];
        #pragma unroll
        for (int ni = 0; ni < 4; ++ni)
            bfr[ni] = *(const f16x8*)&sB[b][(wc * 64 + ni * 16 + lrow) * 32 + lqd * 8];
        #pragma unroll
        for (int mi = 0; mi < 4; ++mi)
            #pragma unroll
            for (int ni = 0; ni < 4; ++ni)
                acc[mi][ni] = __builtin_amdgcn_mfma_f32_16x16x32_f16(bfr[ni], af[mi], acc[mi][ni], 0, 0, 0);
        if (kt < 7) {
            *(uint4*)&sA[b ^ 1][so]        = pk16(ra0, ra1);
            *(uint4*)&sA[b ^ 1][2048 + so] = pk16(ra2, ra3);
            *(uint4*)&sB[b ^ 1][so]        = pk16(rb0, rb1);
            *(uint4*)&sB[b ^ 1][2048 + so] = pk16(rb2, rb3);
        }
    }

    // swapped-C epilogue: lane holds token = mBase+wr*64+mi*16+lrow,
    // channels cg + lqd*4 + r (4 consecutive) -> ushort4 stores.
    const float* bias = (which == 0) ? bq : (which == 1) ? bk : bv;
    u16* dst = (which == 0) ? qb : (which == 1) ? kb : vb;
    #pragma unroll
    for (int ni = 0; ni < 4; ++ni) {
        const int cg = nrow0 + wc * 64 + ni * 16;            // 16-aligned in [0,256)
        const int head = cg >> 5;
        const int d0 = (cg & 31) + lqd * 4;                  // in [0,32), 4-aligned
        const float4 bz4 = *(const float4*)&bias[cg + lqd * 4];
        u16* dh = dst + (size_t)head * (T_TOK * 32);
        #pragma unroll
        for (int mi = 0; mi < 4; ++mi) {
            const int token = mBase + wr * 64 + mi * 16 + lrow;
            ushort4 s;
            s.x = f16b(acc[mi][ni][0] + bz4.x);
            s.y = f16b(acc[mi][ni][1] + bz4.y);
            s.z = f16b(acc[mi][ni][2] + bz4.z);
            s.w = f16b(acc[mi][ni][3] + bz4.w);
            *(ushort4*)&dh[(size_t)token * 32 + d0] = s;
        }
    }
}

// ---------------------------------------------------------------------------
// Out-projection, 128x128 tile (grid (2,98) = 196 blocks): same structure as
// qkv_mfma — 4 waves, 64x64 quadrants, acc 4x4, 16 MFMA : 8 ds_read per
// k-tile. A = ao (f16) via 2x GLD16/buffer; B = wo staged from f32 (2x
// dwordx4 + pk16 + 2x ds_write_b128). SWAPPED mfma(B,A): epilogue = 16x
// float4 stores. ao re-read 2x (was 4x), 1/4 the blocks. XCD-chunked
// bijective swizzle (196 = 4x25 + 4x24).
// ---------------------------------------------------------------------------
__global__ __launch_bounds__(256) void out_mfma(
    const u16* __restrict__ ao, const float* __restrict__ wo,
    const float* __restrict__ bo, float* __restrict__ out) {
    __shared__ __attribute__((aligned(16))) u16 sA[2][128 * 32];
    __shared__ __attribute__((aligned(16))) u16 sB[2][128 * 32];
    const int bid = blockIdx.y * 2 + blockIdx.x;
    const int xcd = bid & 7, loc = bid >> 3;
    const int work = (xcd < 4 ? xcd * 25 : 100 + (xcd - 4) * 24) + loc;
    const int nBase = (work & 1) * 128;
    const int mBase = (work >> 1) * 128;
    const int tid = threadIdx.x, wv_ = tid >> 6, ln = tid & 63;
    const int lrow = ln & 15, lqd = ln >> 4;
    const int wr = wv_ >> 1, wc = wv_ & 1;         // wave quadrant (2x2)

    const int arow = tid >> 2, acol = (tid & 3) * 8;
    const size_t gA = (size_t)(mBase + arow) * EMB + acol;     // ao, u16 units
    const float* gBf = wo + (size_t)(nBase + arow) * EMB + acol;
    const int lA = wv_ * 512;                      // wave-uniform GLD16 dest
    const int so = tid * 8;

    f32x4 acc[4][4];
    #pragma unroll
    for (int mi = 0; mi < 4; ++mi)
        #pragma unroll
        for (int ni = 0; ni < 4; ++ni) acc[mi][ni] = (f32x4){0.f, 0.f, 0.f, 0.f};

    GLD16(ao + gA,            &sA[0][lA]);
    GLD16(ao + gA + 64 * EMB, &sA[0][2048 + lA]);
    {
        const float4 rb0 = *(const float4*)(gBf);
        const float4 rb1 = *(const float4*)(gBf + 4);
        const float4 rb2 = *(const float4*)(gBf + 64 * EMB);
        const float4 rb3 = *(const float4*)(gBf + 64 * EMB + 4);
        *(uint4*)&sB[0][so]        = pk16(rb0, rb1);
        *(uint4*)&sB[0][2048 + so] = pk16(rb2, rb3);
    }

    for (int kt = 0; kt < 8; ++kt) {
        const int b = kt & 1;
        __syncthreads();
        float4 rb0, rb1, rb2, rb3;
        if (kt < 7) {
            const int k0 = (kt + 1) * 32;
            GLD16(ao + gA + k0,            &sA[b ^ 1][lA]);
            GLD16(ao + gA + k0 + 64 * EMB, &sA[b ^ 1][2048 + lA]);
            rb0 = *(const float4*)(gBf + k0);
            rb1 = *(const float4*)(gBf + k0 + 4);
            rb2 = *(const float4*)(gBf + k0 + 64 * EMB);
            rb3 = *(const float4*)(gBf + k0 + 64 * EMB + 4);
        }
        f16x8 af[4], bfr[4];
        #pragma unroll
        for (int mi = 0; mi < 4; ++mi)
            af[mi] = *(const f16x8*)&sA[b][(wr * 64 + mi * 16 + lrow) * 32 + lqd * 8];
        #pragma unroll
        for (int ni = 0; ni < 4; ++ni)
            bfr[ni] = *(const f16x8*)&sB[b][(wc * 64 + ni * 16 + lrow) * 32 + lqd * 8];
        #pragma unroll
        for (int mi = 0; mi < 4; ++mi)
            #pragma unroll
            for (int ni = 0; ni < 4; ++ni)
                acc[mi][ni] = __builtin_amdgcn_mfma_f32_16x16x32_f16(bfr[ni], af[mi], acc[mi][ni], 0, 0, 0);
        if (kt < 7) {
            *(uint4*)&sB[b ^ 1][so]        = pk16(rb0, rb1);
            *(uint4*)&sB[b ^ 1][2048 + so] = pk16(rb2, rb3);
        }
    }

    // swapped-C epilogue: lane holds token = mBase+wr*64+mi*16+lrow,
    // 4 consecutive out-cols per (ni) -> float4 stores.
    #pragma unroll
    for (int ni = 0; ni < 4; ++ni) {
        const int nc0 = nBase + wc * 64 + ni * 16 + lqd * 4;
        const float4 bz4 = *(const float4*)&bo[nc0];
        #pragma unroll
        for (int mi = 0; mi < 4; ++mi) {
            const int token = mBase + wr * 64 + mi * 16 + lrow;
            float4 o;
            o.x = acc[mi][ni][0] + bz4.x;
            o.y = acc[mi][ni][1] + bz4.y;
            o.z = acc[mi][ni][2] + bz4.z;
            o.w = acc[mi][ni][3] + bz4.w;
            *(float4*)&out[(size_t)token * EMB + nc0] = o;
        }
    }
}

// ---------------------------------------------------------------------------
// Attention: K staged in LDS (bulk coalesced b128; OOB -> exact ZEROS, which
// the zero-padded reference requires: OOB neighbors contribute exp(0)=1 to
// the softmax denominator). V^T staged pair-wise (b32 scatter). Swapped-
// operand MFMA: S^T = mfma(K,Q) so softmax is lane-local (no max pass),
// sum = 31 VALU adds + 2 shfls. P via 8 ds_write_b64; PV = mfma(V^T,P)
// gives O^T -> 2x 8B global stores. sP overlays sK after barrier 2.
// LDS 30720 B -> 5 blk/CU.
// ---------------------------------------------------------------------------
__global__ __launch_bounds__(256, 5) void attn_kernel(
    const u16* __restrict__ qb, const u16* __restrict__ kb, const u16* __restrict__ vb,
    u16* __restrict__ ao) {
    __shared__ __attribute__((aligned(16))) u16 smem[15360];   // 30720 B
    u16* sVT = smem;            // [32][VTSTR=208]  V^T (persists)
    u16* sK  = smem + 6656;     // [208][KSTR=40]   K halo, rows>=196 zero
    u16* sP  = smem + 6656;     // [4][16][PSTR=136] overlays sK after barrier 2

    const int tid = threadIdx.x;
    const int w = tid >> 6, ln = tid & 63;
    const int lrow = ln & 15, lqd = ln >> 4;
    const int img = blockIdx.z >> 3, head = blockIdx.z & 7;
    const int ty0 = blockIdx.y * 8, tx0 = blockIdx.x * 8;
    const int base8 = (28 * w) & ~7;   // {0, 24, 56, 80}

    const u16* kbh = kb + (size_t)head * (T_TOK * 32);
    const u16* vbh = vb + (size_t)head * (T_TOK * 32);
    const u16* qbh = qb + (size_t)head * (T_TOK * 32);

    // ---- stage K [p][d] (b128) and V^T [d][p] (pair-wise b32 scatter) ----
    for (int i = tid; i < 1248; i += 256) {
        if (i < 832) {
            const int p = i >> 2, c = i & 3;
            const int pyh = p / 14, pxh = p - pyh * 14;
            const int gy = ty0 - 3 + pyh, gx = tx0 - 3 + pxh;
            const bool ok = (p < HALO) & ((unsigned)gy < 56u) & ((unsigned)gx < 56u);
            u16* dstk = sK + p * KSTR + c * 8;
            if (ok) {
                const size_t tt = (size_t)((img * IMG + gy) * IMG + gx) * 32;
                *(uint4*)dstk = *(const uint4*)(kbh + tt + c * 8);
            } else {
                *(uint4*)dstk = (uint4){0u, 0u, 0u, 0u};
            }
        } else {
            const int j = i - 832;          // 0..415
            const int pp = j >> 2, c = j & 3;
            const int p0 = pp * 2;          // pixels p0, p0+1 (same halo row)
            const int pyh = p0 / 14, pxh = p0 - pyh * 14;
            const int gy = ty0 - 3 + pyh, gx = tx0 - 3 + pxh;
            const bool oky = (p0 < HALO) & ((unsigned)gy < 56u);
            const bool ok0 = oky & ((unsigned)gx < 56u);
            const bool ok1 = oky & ((unsigned)(gx + 1) < 56u);
            const long long tt = (long long)((img * IMG + gy) * IMG + gx) * 32;
            const uint4 u0 = ok0 ? *(const uint4*)(vbh + tt + c * 8)
                                 : (uint4){0u, 0u, 0u, 0u};
            const uint4 u1 = ok1 ? *(const uint4*)(vbh + tt + 32 + c * 8)
                                 : (uint4){0u, 0u, 0u, 0u};
            u16* dv = sVT + (c * 8) * VTSTR + p0;
            *(u32*)&dv[0 * VTSTR] = (u0.x & 0xffffu) | (u1.x << 16);
            *(u32*)&dv[1 * VTSTR] = (u0.x >> 16)     | (u1.x & 0xffff0000u);
            *(u32*)&dv[2 * VTSTR] = (u0.y & 0xffffu) | (u1.y << 16);
            *(u32*)&dv[3 * VTSTR] = (u0.y >> 16)     | (u1.y & 0xffff0000u);
            *(u32*)&dv[4 * VTSTR] = (u0.z & 0xffffu) | (u1.z << 16);
            *(u32*)&dv[5 * VTSTR] = (u0.z >> 16)     | (u1.z & 0xffff0000u);
            *(u32*)&dv[6 * VTSTR] = (u0.w & 0xffffu) | (u1.w << 16);
            *(u32*)&dv[7 * VTSTR] = (u0.w >> 16)     | (u1.w & 0xffff0000u);
        }
    }

    // ---- Q fragment (row = this lane's query pixel = w*16+lrow) ----
    const int qpy = 2 * w + (lrow >> 3), qpx = lrow & 7;   // pixel within 8x8 tile
    const size_t qtok = ((size_t)img * IMG + ty0 + qpy) * IMG + tx0 + qpx;
    const f16x8 aq = *(const f16x8*)&qbh[qtok * 32 + lqd * 8];
    __syncthreads();

    // ---- QK^T swapped: lane holds S[qpix=lrow][col = base8 + t*16 + lqd*4+r]
    f32x4 ct[8];
    #pragma unroll
    for (int t = 0; t < 8; ++t) ct[t] = (f32x4){0.f, 0.f, 0.f, 0.f};
    #pragma unroll
    for (int t = 0; t < 8; ++t) {
        const f16x8 bk = *(const f16x8*)&sK[(base8 + t * 16 + lrow) * KSTR + lqd * 8];
        ct[t] = __builtin_amdgcn_mfma_f32_16x16x32_f16(bk, aq, ct[t], 0, 0, 0);
    }

    // ---- mask + exp2 (no max pass: |logits| small, f32-safe), lane-local sum
    float ssum = 0.f;
    #pragma unroll
    for (int t = 0; t < 8; ++t) {
        #pragma unroll
        for (int r = 0; r < 4; ++r) {
            const int col = base8 + t * 16 + lqd * 4 + r;
            const int hy = col / 14, hx = col - 14 * hy;
            const bool ok = ((unsigned)(hy - qpy) < 7u) &
                            ((unsigned)(hx - qpx) < 7u) & (col < HALO);
            const float e = ok ? exp2f(ct[t][r] * SCALE2) : 0.f;
            ct[t][r] = e;
            ssum += e;
        }
    }
    ssum += __shfl_xor(ssum, 16);
    ssum += __shfl_xor(ssum, 32);
    const float inv = 1.0f / ssum;

    __syncthreads();   // all QK reads of sK done; safe to overlay with P

    // ---- P (f16) to LDS: row = qpix (lrow), 4 consecutive cols per write ----
    u16* sPw = sP + w * 16 * PSTR;
    #pragma unroll
    for (int t = 0; t < 8; ++t) {
        ushort4 pw;
        pw.x = f16b(ct[t][0]);
        pw.y = f16b(ct[t][1]);
        pw.z = f16b(ct[t][2]);
        pw.w = f16b(ct[t][3]);
        *(ushort4*)&sPw[lrow * PSTR + t * 16 + lqd * 4] = pw;
    }

    // ---- PV swapped: O^T[d][qpix] = mfma(A=V^T rows=d, B=P rows=qpix) ----
    f32x4 o0 = (f32x4){0.f, 0.f, 0.f, 0.f};
    f32x4 o1 = (f32x4){0.f, 0.f, 0.f, 0.f};
    #pragma unroll
    for (int ks = 0; ks < 4; ++ks) {
        const f16x8 ap  = *(const f16x8*)&sPw[lrow * PSTR + ks * 32 + lqd * 8];
        const f16x8 av0 = *(const f16x8*)&sVT[lrow * VTSTR + base8 + ks * 32 + lqd * 8];
        const f16x8 av1 = *(const f16x8*)&sVT[(16 + lrow) * VTSTR + base8 + ks * 32 + lqd * 8];
        o0 = __builtin_amdgcn_mfma_f32_16x16x32_f16(av0, ap, o0, 0, 0, 0);
        o1 = __builtin_amdgcn_mfma_f32_16x16x32_f16(av1, ap, o1, 0, 0, 0);
    }

    // ---- epilogue: lane holds O[qpix=lrow][d = lqd*4 + r (+16)] ----
    const size_t base = qtok * EMB + head * 32;
    ushort4 s0, s1;
    s0.x = f16b(o0[0] * inv); s0.y = f16b(o0[1] * inv);
    s0.z = f16b(o0[2] * inv); s0.w = f16b(o0[3] * inv);
    s1.x = f16b(o1[0] * inv); s1.y = f16b(o1[1] * inv);
    s1.z = f16b(o1[2] * inv); s1.w = f16b(o1[3] * inv);
    *(ushort4*)&ao[base + lqd * 4]      = s0;
    *(ushort4*)&ao[base + 16 + lqd * 4] = s1;
}

extern "C" void kernel_launch(void* const* d_in, const int* in_sizes, int n_in,
                              void* d_out, int out_size, void* d_ws, size_t ws_size,
                              hipStream_t stream) {
    const float* x  = (const float*)d_in[0];
    const float* wq = (const float*)d_in[1];
    const float* wk = (const float*)d_in[2];
    const float* wv = (const float*)d_in[3];
    const float* wo = (const float*)d_in[4];
    const float* bq = (const float*)d_in[5];
    const float* bk = (const float*)d_in[6];
    const float* bv = (const float*)d_in[7];
    const float* bo = (const float*)d_in[8];
    float* out = (float*)d_out;

    char* ws = (char*)d_ws;
    u16* qb = (u16*)(ws);                // 6,422,528 B  head-blocked [8][12544][32] f16
    u16* kb = (u16*)(ws +  6422528);     // 6,422,528 B
    u16* vb = (u16*)(ws + 12845056);     // 6,422,528 B
    u16* ao = (u16*)(ws + 19267584);     // 6,422,528 B  attn out f16 [tok][256] -> 25,690,112 B

    qkv_mfma<<<dim3(6, 98), 256, 0, stream>>>(x, wq, wk, wv, bq, bk, bv, qb, kb, vb);
    attn_kernel<<<dim3(7, 7, 32), 256, 0, stream>>>(qb, kb, vb, ao);
    out_mfma<<<dim3(2, 98), 256, 0, stream>>>(ao, wo, bo, out);
}

// Round 8
// 118.337 us; speedup vs baseline: 1.0651x; 1.0651x over previous
//
#include <hip/hip_runtime.h>

typedef unsigned int u32;
typedef unsigned short u16;
typedef _Float16 f16;
typedef __attribute__((ext_vector_type(8))) _Float16 f16x8;
typedef __attribute__((ext_vector_type(4))) float f32x4;

#define T_TOK 12544   // 4*56*56
#define EMB   256
#define IMG   56
// SCALE * log2(e): softmax via exp2 is mathematically identical
#define SCALE2 0.25503486f
#define HALO  196
#define KSTR  40      // sK row stride (u16)
#define VTSTR 208     // sVT row stride (u16) — must stay %8==0 for b128 PV reads
#define PSTR  136     // sP row stride (u16): 128-col window + 8 pad

__device__ __forceinline__ u16 f16b(float f) {
    const f16 h = (f16)f;                 // v_cvt_f16_f32, RTNE
    return __builtin_bit_cast(u16, h);
}
__device__ __forceinline__ u32 pk2(float lo, float hi) {
    return (u32)f16b(lo) | ((u32)f16b(hi) << 16);
}
__device__ __forceinline__ uint4 pk16(const float4 a, const float4 b) {
    uint4 r;
    r.x = pk2(a.x, a.y); r.y = pk2(a.z, a.w);
    r.z = pk2(b.x, b.y); r.w = pk2(b.z, b.w);
    return r;
}

// async global->LDS, 16B/lane; LDS dest must be wave-uniform base + lane*16
#define GLD16(g, l) __builtin_amdgcn_global_load_lds( \
    (const __attribute__((address_space(1))) u32*)(g), \
    (__attribute__((address_space(3))) u32*)(l), 16, 0, 0)

// ---------------------------------------------------------------------------
// QKV GEMM, 128x128 tile (588 blocks): 4 waves, each a 64x64 quadrant
// (acc 4x4). A,B staged directly from f32 (dwordx4 + cvt + ds_write_b128
// after the MFMA phase). SWAPPED mfma(B,A): lane owns one token with 4
// consecutive channels per reg-quad -> epilogue = 16x ushort4 stores.
// Double-buffered, 1 barrier/k-tile, XCD-chunked swizzle.
// Output HEAD-BLOCKED [head][token][32] f16.
// ---------------------------------------------------------------------------
__global__ __launch_bounds__(256) void qkv_mfma(
    const float* __restrict__ xf,
    const float* __restrict__ wq, const float* __restrict__ wk, const float* __restrict__ wv,
    const float* __restrict__ bq, const float* __restrict__ bk, const float* __restrict__ bv,
    u16* __restrict__ qb, u16* __restrict__ kb, u16* __restrict__ vb) {
    __shared__ __attribute__((aligned(16))) u16 sA[2][128 * 32];
    __shared__ __attribute__((aligned(16))) u16 sB[2][128 * 32];
    const int bid = blockIdx.y * 6 + blockIdx.x;
    const int xcd = bid & 7, loc = bid >> 3;
    const int work = (xcd < 4 ? xcd * 74 : 296 + (xcd - 4) * 73) + loc;
    const int nBase = (work % 6) * 128;            // 0..767 (stacked qkv)
    const int mBase = (work / 6) * 128;
    const int tid = threadIdx.x, wv_ = tid >> 6, ln = tid & 63;
    const int lrow = ln & 15, lqd = ln >> 4;
    const int wr = wv_ >> 1, wc = wv_ & 1;         // wave quadrant (2x2)

    const int which = nBase >> 8;   // 0=q, 1=k, 2=v (uniform per block)
    const float* wsrc = (which == 0) ? wq : (which == 1) ? wk : wv;
    const int nrow0 = nBase & 255;

    // staging map: thread -> (row = tid>>2 and +64, cols (tid&3)*8 .. +8)
    const int arow = tid >> 2, acol = (tid & 3) * 8;
    const float* gAf = xf   + (size_t)(mBase + arow) * EMB + acol;
    const float* gBf = wsrc + (size_t)(nrow0 + arow) * EMB + acol;
    const int so = tid * 8;                        // u16 offset (linear, conflict-free)

    f32x4 acc[4][4];
    #pragma unroll
    for (int mi = 0; mi < 4; ++mi)
        #pragma unroll
        for (int ni = 0; ni < 4; ++ni) acc[mi][ni] = (f32x4){0.f, 0.f, 0.f, 0.f};

    // prologue: stage k-tile 0 into buffer 0
    {
        const float4 ra0 = *(const float4*)(gAf);
        const float4 ra1 = *(const float4*)(gAf + 4);
        const float4 ra2 = *(const float4*)(gAf + 64 * EMB);
        const float4 ra3 = *(const float4*)(gAf + 64 * EMB + 4);
        const float4 rb0 = *(const float4*)(gBf);
        const float4 rb1 = *(const float4*)(gBf + 4);
        const float4 rb2 = *(const float4*)(gBf + 64 * EMB);
        const float4 rb3 = *(const float4*)(gBf + 64 * EMB + 4);
        *(uint4*)&sA[0][so]        = pk16(ra0, ra1);
        *(uint4*)&sA[0][2048 + so] = pk16(ra2, ra3);
        *(uint4*)&sB[0][so]        = pk16(rb0, rb1);
        *(uint4*)&sB[0][2048 + so] = pk16(rb2, rb3);
    }

    for (int kt = 0; kt < 8; ++kt) {
        const int b = kt & 1;
        __syncthreads();
        float4 ra0, ra1, ra2, ra3, rb0, rb1, rb2, rb3;
        if (kt < 7) {
            const int k0 = (kt + 1) * 32;
            ra0 = *(const float4*)(gAf + k0);
            ra1 = *(const float4*)(gAf + k0 + 4);
            ra2 = *(const float4*)(gAf + k0 + 64 * EMB);
            ra3 = *(const float4*)(gAf + k0 + 64 * EMB + 4);
            rb0 = *(const float4*)(gBf + k0);
            rb1 = *(const float4*)(gBf + k0 + 4);
            rb2 = *(const float4*)(gBf + k0 + 64 * EMB);
            rb3 = *(const float4*)(gBf + k0 + 64 * EMB + 4);
        }
        f16x8 af[4], bfr[4];
        #pragma unroll
        for (int mi = 0; mi < 4; ++mi)
            af[mi] = *(const f16x8*)&sA[b][(wr * 64 + mi * 16 + lrow) * 32 + lqd * 8];
        #pragma unroll
        for (int ni = 0; ni < 4; ++ni)
            bfr[ni] = *(const f16x8*)&sB[b][(wc * 64 + ni * 16 + lrow) * 32 + lqd * 8];
        #pragma unroll
        for (int mi = 0; mi < 4; ++mi)
            #pragma unroll
            for (int ni = 0; ni < 4; ++ni)
                acc[mi][ni] = __builtin_amdgcn_mfma_f32_16x16x32_f16(bfr[ni], af[mi], acc[mi][ni], 0, 0, 0);
        if (kt < 7) {
            *(uint4*)&sA[b ^ 1][so]        = pk16(ra0, ra1);
            *(uint4*)&sA[b ^ 1][2048 + so] = pk16(ra2, ra3);
            *(uint4*)&sB[b ^ 1][so]        = pk16(rb0, rb1);
            *(uint4*)&sB[b ^ 1][2048 + so] = pk16(rb2, rb3);
        }
    }

    // swapped-C epilogue: lane holds token = mBase+wr*64+mi*16+lrow,
    // channels cg + lqd*4 + r (4 consecutive) -> ushort4 stores.
    const float* bias = (which == 0) ? bq : (which == 1) ? bk : bv;
    u16* dst = (which == 0) ? qb : (which == 1) ? kb : vb;
    #pragma unroll
    for (int ni = 0; ni < 4; ++ni) {
        const int cg = nrow0 + wc * 64 + ni * 16;            // 16-aligned in [0,256)
        const int head = cg >> 5;
        const int d0 = (cg & 31) + lqd * 4;                  // in [0,32), 4-aligned
        const float4 bz4 = *(const float4*)&bias[cg + lqd * 4];
        u16* dh = dst + (size_t)head * (T_TOK * 32);
        #pragma unroll
        for (int mi = 0; mi < 4; ++mi) {
            const int token = mBase + wr * 64 + mi * 16 + lrow;
            ushort4 s;
            s.x = f16b(acc[mi][ni][0] + bz4.x);
            s.y = f16b(acc[mi][ni][1] + bz4.y);
            s.z = f16b(acc[mi][ni][2] + bz4.z);
            s.w = f16b(acc[mi][ni][3] + bz4.w);
            *(ushort4*)&dh[(size_t)token * 32 + d0] = s;
        }
    }
}

// ---------------------------------------------------------------------------
// Out-projection, 64x64 tile (784 blocks, ~3 blk/CU): A = ao (f16) via
// GLD16; B = wo staged directly from f32. SWAPPED mfma(B,A): epilogue =
// 4x float4 stores. Double-buffered, 1 barrier/k-tile, XCD-chunked swizzle
// (784 = 8x98). [r7's 128^2 tile regressed: 196 blocks = 1/CU, staging
// latency exposed at barriers — keep 64^2.]
// ---------------------------------------------------------------------------
__global__ __launch_bounds__(256) void out_mfma(
    const u16* __restrict__ ao, const float* __restrict__ wo,
    const float* __restrict__ bo, float* __restrict__ out) {
    __shared__ __attribute__((aligned(16))) u16 sA[2][64 * 32];
    __shared__ __attribute__((aligned(16))) u16 sB[2][64 * 32];
    const int bid = blockIdx.y * 4 + blockIdx.x;
    const int work = (bid & 7) * 98 + (bid >> 3);
    const int nBase = (work & 3) * 64;
    const int mBase = (work >> 2) * 64;
    const int tid = threadIdx.x, wv_ = tid >> 6, ln = tid & 63;
    const int lrow = ln & 15, lqd = ln >> 4;
    const int rA = tid >> 2, kcA = tid & 3;
    const size_t gA = (size_t)(mBase + rA) * EMB + kcA * 8;
    const int lA = wv_ * 512;

    const int brow = tid >> 2, bcol = (tid & 3) * 8;
    const float* gBf = wo + (size_t)(nBase + brow) * EMB + bcol;
    const int so = tid * 8;

    f32x4 acc[4];
    #pragma unroll
    for (int mi = 0; mi < 4; ++mi) acc[mi] = (f32x4){0.f, 0.f, 0.f, 0.f};

    GLD16(ao + gA, &sA[0][lA]);
    {
        const float4 rb0 = *(const float4*)(gBf);
        const float4 rb1 = *(const float4*)(gBf + 4);
        *(uint4*)&sB[0][so] = pk16(rb0, rb1);
    }

    for (int kt = 0; kt < 8; ++kt) {
        const int b = kt & 1;
        __syncthreads();
        float4 rb0, rb1;
        if (kt < 7) {
            const int k0 = (kt + 1) * 32;
            GLD16(ao + gA + k0, &sA[b ^ 1][lA]);
            rb0 = *(const float4*)(gBf + k0);
            rb1 = *(const float4*)(gBf + k0 + 4);
        }
        f16x8 af[4];
        #pragma unroll
        for (int mi = 0; mi < 4; ++mi)
            af[mi] = *(const f16x8*)&sA[b][(mi * 16 + lrow) * 32 + lqd * 8];
        const f16x8 bf = *(const f16x8*)&sB[b][(wv_ * 16 + lrow) * 32 + lqd * 8];
        #pragma unroll
        for (int mi = 0; mi < 4; ++mi)
            acc[mi] = __builtin_amdgcn_mfma_f32_16x16x32_f16(bf, af[mi], acc[mi], 0, 0, 0);
        if (kt < 7) {
            *(uint4*)&sB[b ^ 1][so] = pk16(rb0, rb1);
        }
    }

    // swapped-C epilogue: lane holds token = mBase+mi*16+lrow,
    // 4 consecutive out-cols nc0..nc0+3 -> float4 stores.
    const int nc0 = nBase + wv_ * 16 + lqd * 4;
    const float4 bz4 = *(const float4*)&bo[nc0];
    #pragma unroll
    for (int mi = 0; mi < 4; ++mi) {
        const int token = mBase + mi * 16 + lrow;
        float4 o;
        o.x = acc[mi][0] + bz4.x;
        o.y = acc[mi][1] + bz4.y;
        o.z = acc[mi][2] + bz4.z;
        o.w = acc[mi][3] + bz4.w;
        *(float4*)&out[(size_t)token * EMB + nc0] = o;
    }
}

// ---------------------------------------------------------------------------
// Attention: K staged in LDS (bulk coalesced b128; OOB -> exact ZEROS, which
// the zero-padded reference requires). V^T staged pair-wise (b32 scatter).
// Swapped-operand MFMA: S^T = mfma(K,Q), lane-local softmax (no max pass),
// sum = 31 VALU adds + 2 shfls. P via ds_write_b64; PV = mfma(V^T,P) gives
// O^T -> 2x 8B stores. sP overlays sK after barrier 2. LDS 30720 B -> 5/CU.
// XCD-LOCALITY REMAP: all 49 tile-blocks of one (img,head) share a residue
// class mod 8 -> one XCD's L2 holds that (img,head)'s K/V/Q once instead of
// all 8 XCDs refetching it (bijective: c*4 + idx/49, tile = idx%49).
// ---------------------------------------------------------------------------
__global__ __launch_bounds__(256, 5) void attn_kernel(
    const u16* __restrict__ qb, const u16* __restrict__ kb, const u16* __restrict__ vb,
    u16* __restrict__ ao) {
    __shared__ __attribute__((aligned(16))) u16 smem[15360];   // 30720 B
    u16* sVT = smem;            // [32][VTSTR=208]  V^T (persists)
    u16* sK  = smem + 6656;     // [208][KSTR=40]   K halo, rows>=196 zero
    u16* sP  = smem + 6656;     // [4][16][PSTR=136] overlays sK after barrier 2

    const int tid = threadIdx.x;
    const int w = tid >> 6, ln = tid & 63;
    const int lrow = ln & 15, lqd = ln >> 4;

    // XCD-locality remap (1568 blocks = 8 residues x 196; 196 = 4 ih x 49)
    const int bid = blockIdx.x + 7 * blockIdx.y + 49 * blockIdx.z;
    const int c8 = bid & 7, idx = bid >> 3;
    const int q49 = idx / 49;                  // 0..3
    const int tile = idx - q49 * 49;           // 0..48
    const int ihead = c8 * 4 + q49;            // 0..31
    const int img = ihead >> 3, head = ihead & 7;
    const int tyq = tile / 7;
    const int ty0 = tyq * 8, tx0 = (tile - tyq * 7) * 8;
    const int base8 = (28 * w) & ~7;   // {0, 24, 56, 80}

    const u16* kbh = kb + (size_t)head * (T_TOK * 32);
    const u16* vbh = vb + (size_t)head * (T_TOK * 32);
    const u16* qbh = qb + (size_t)head * (T_TOK * 32);

    // ---- stage K [p][d] (b128) and V^T [d][p] (pair-wise b32 scatter) ----
    for (int i = tid; i < 1248; i += 256) {
        if (i < 832) {
            const int p = i >> 2, c = i & 3;
            const int pyh = p / 14, pxh = p - pyh * 14;
            const int gy = ty0 - 3 + pyh, gx = tx0 - 3 + pxh;
            const bool ok = (p < HALO) & ((unsigned)gy < 56u) & ((unsigned)gx < 56u);
            u16* dstk = sK + p * KSTR + c * 8;
            if (ok) {
                const size_t tt = (size_t)((img * IMG + gy) * IMG + gx) * 32;
                *(uint4*)dstk = *(const uint4*)(kbh + tt + c * 8);
            } else {
                *(uint4*)dstk = (uint4){0u, 0u, 0u, 0u};
            }
        } else {
            const int j = i - 832;          // 0..415
            const int pp = j >> 2, c = j & 3;
            const int p0 = pp * 2;          // pixels p0, p0+1 (same halo row)
            const int pyh = p0 / 14, pxh = p0 - pyh * 14;
            const int gy = ty0 - 3 + pyh, gx = tx0 - 3 + pxh;
            const bool oky = (p0 < HALO) & ((unsigned)gy < 56u);
            const bool ok0 = oky & ((unsigned)gx < 56u);
            const bool ok1 = oky & ((unsigned)(gx + 1) < 56u);
            const long long tt = (long long)((img * IMG + gy) * IMG + gx) * 32;
            const uint4 u0 = ok0 ? *(const uint4*)(vbh + tt + c * 8)
                                 : (uint4){0u, 0u, 0u, 0u};
            const uint4 u1 = ok1 ? *(const uint4*)(vbh + tt + 32 + c * 8)
                                 : (uint4){0u, 0u, 0u, 0u};
            u16* dv = sVT + (c * 8) * VTSTR + p0;
            *(u32*)&dv[0 * VTSTR] = (u0.x & 0xffffu) | (u1.x << 16);
            *(u32*)&dv[1 * VTSTR] = (u0.x >> 16)     | (u1.x & 0xffff0000u);
            *(u32*)&dv[2 * VTSTR] = (u0.y & 0xffffu) | (u1.y << 16);
            *(u32*)&dv[3 * VTSTR] = (u0.y >> 16)     | (u1.y & 0xffff0000u);
            *(u32*)&dv[4 * VTSTR] = (u0.z & 0xffffu) | (u1.z << 16);
            *(u32*)&dv[5 * VTSTR] = (u0.z >> 16)     | (u1.z & 0xffff0000u);
            *(u32*)&dv[6 * VTSTR] = (u0.w & 0xffffu) | (u1.w << 16);
            *(u32*)&dv[7 * VTSTR] = (u0.w >> 16)     | (u1.w & 0xffff0000u);
        }
    }

    // ---- Q fragment (row = this lane's query pixel = w*16+lrow) ----
    const int qpy = 2 * w + (lrow >> 3), qpx = lrow & 7;   // pixel within 8x8 tile
    const size_t qtok = ((size_t)img * IMG + ty0 + qpy) * IMG + tx0 + qpx;
    const f16x8 aq = *(const f16x8*)&qbh[qtok * 32 + lqd * 8];
    __syncthreads();

    // ---- QK^T swapped: lane holds S[qpix=lrow][col = base8 + t*16 + lqd*4+r]
    f32x4 ct[8];
    #pragma unroll
    for (int t = 0; t < 8; ++t) ct[t] = (f32x4){0.f, 0.f, 0.f, 0.f};
    #pragma unroll
    for (int t = 0; t < 8; ++t) {
        const f16x8 bk = *(const f16x8*)&sK[(base8 + t * 16 + lrow) * KSTR + lqd * 8];
        ct[t] = __builtin_amdgcn_mfma_f32_16x16x32_f16(bk, aq, ct[t], 0, 0, 0);
    }

    // ---- mask + exp2 (no max pass: |logits| small, f32-safe), lane-local sum
    float ssum = 0.f;
    #pragma unroll
    for (int t = 0; t < 8; ++t) {
        #pragma unroll
        for (int r = 0; r < 4; ++r) {
            const int col = base8 + t * 16 + lqd * 4 + r;
            const int hy = col / 14, hx = col - 14 * hy;
            const bool ok = ((unsigned)(hy - qpy) < 7u) &
                            ((unsigned)(hx - qpx) < 7u) & (col < HALO);
            const float e = ok ? exp2f(ct[t][r] * SCALE2) : 0.f;
            ct[t][r] = e;
            ssum += e;
        }
    }
    ssum += __shfl_xor(ssum, 16);
    ssum += __shfl_xor(ssum, 32);
    const float inv = 1.0f / ssum;

    __syncthreads();   // all QK reads of sK done; safe to overlay with P

    // ---- P (f16) to LDS: row = qpix (lrow), 4 consecutive cols per write ----
    u16* sPw = sP + w * 16 * PSTR;
    #pragma unroll
    for (int t = 0; t < 8; ++t) {
        ushort4 pw;
        pw.x = f16b(ct[t][0]);
        pw.y = f16b(ct[t][1]);
        pw.z = f16b(ct[t][2]);
        pw.w = f16b(ct[t][3]);
        *(ushort4*)&sPw[lrow * PSTR + t * 16 + lqd * 4] = pw;
    }

    // ---- PV swapped: O^T[d][qpix] = mfma(A=V^T rows=d, B=P rows=qpix) ----
    f32x4 o0 = (f32x4){0.f, 0.f, 0.f, 0.f};
    f32x4 o1 = (f32x4){0.f, 0.f, 0.f, 0.f};
    #pragma unroll
    for (int ks = 0; ks < 4; ++ks) {
        const f16x8 ap  = *(const f16x8*)&sPw[lrow * PSTR + ks * 32 + lqd * 8];
        const f16x8 av0 = *(const f16x8*)&sVT[lrow * VTSTR + base8 + ks * 32 + lqd * 8];
        const f16x8 av1 = *(const f16x8*)&sVT[(16 + lrow) * VTSTR + base8 + ks * 32 + lqd * 8];
        o0 = __builtin_amdgcn_mfma_f32_16x16x32_f16(av0, ap, o0, 0, 0, 0);
        o1 = __builtin_amdgcn_mfma_f32_16x16x32_f16(av1, ap, o1, 0, 0, 0);
    }

    // ---- epilogue: lane holds O[qpix=lrow][d = lqd*4 + r (+16)] ----
    const size_t base = qtok * EMB + head * 32;
    ushort4 s0, s1;
    s0.x = f16b(o0[0] * inv); s0.y = f16b(o0[1] * inv);
    s0.z = f16b(o0[2] * inv); s0.w = f16b(o0[3] * inv);
    s1.x = f16b(o1[0] * inv); s1.y = f16b(o1[1] * inv);
    s1.z = f16b(o1[2] * inv); s1.w = f16b(o1[3] * inv);
    *(ushort4*)&ao[base + lqd * 4]      = s0;
    *(ushort4*)&ao[base + 16 + lqd * 4] = s1;
}

extern "C" void kernel_launch(void* const* d_in, const int* in_sizes, int n_in,
                              void* d_out, int out_size, void* d_ws, size_t ws_size,
                              hipStream_t stream) {
    const float* x  = (const float*)d_in[0];
    const float* wq = (const float*)d_in[1];
    const float* wk = (const float*)d_in[2];
    const float* wv = (const float*)d_in[3];
    const float* wo = (const float*)d_in[4];
    const float* bq = (const float*)d_in[5];
    const float* bk = (const float*)d_in[6];
    const float* bv = (const float*)d_in[7];
    const float* bo = (const float*)d_in[8];
    float* out = (float*)d_out;

    char* ws = (char*)d_ws;
    u16* qb = (u16*)(ws);                // 6,422,528 B  head-blocked [8][12544][32] f16
    u16* kb = (u16*)(ws +  6422528);     // 6,422,528 B
    u16* vb = (u16*)(ws + 12845056);     // 6,422,528 B
    u16* ao = (u16*)(ws + 19267584);     // 6,422,528 B  attn out f16 [tok][256] -> 25,690,112 B

    qkv_mfma<<<dim3(6, 98), 256, 0, stream>>>(x, wq, wk, wv, bq, bk, bv, qb, kb, vb);
    attn_kernel<<<dim3(7, 7, 32), 256, 0, stream>>>(qb, kb, vb, ao);
    out_mfma<<<dim3(4, 196), 256, 0, stream>>>(ao, wo, bo, out);
}